// Round 4
// baseline (341.795 us; speedup 1.0000x reference)
//
#include <hip/hip_runtime.h>
#include <math.h>

// K=30 bands, B=4, T=512, N=128, Vd=64, NKB=120
typedef __attribute__((ext_vector_type(8))) short bf16x8;
typedef __attribute__((ext_vector_type(4))) float f32x4;

#define MFMA(a, b, c) __builtin_amdgcn_mfma_f32_16x16x32_bf16((a), (b), (c), 0, 0, 0)

__device__ inline unsigned short f2b(float f) {
    unsigned u = __builtin_bit_cast(unsigned, f);
    u += 0x7FFF + ((u >> 16) & 1);
    return (unsigned short)(u >> 16);
}

// ws byte offsets
static constexpr size_t OFF_XB    = 0;           // bf16 120*512*128
static constexpr size_t OFF_Q     = 15728640;    // bf16 120*512*128
static constexpr size_t OFF_K     = 31457280;    // bf16 120*512*128
static constexpr size_t OFF_VT    = 47185920;    // bf16 120*64*512
static constexpr size_t OFF_OM    = 55050240;    // bf16 120*512*64
static constexpr size_t OFF_WQ    = 62914560;    // bf16 30*128*128
static constexpr size_t OFF_WK    = 63897600;    // bf16 30*128*128
static constexpr size_t OFF_WV    = 64880640;    // bf16 30*64*128
static constexpr size_t OFF_WO    = 65372160;    // bf16 30*128*64
static constexpr size_t OFF_RS    = 65863680;    // f32 120*512*8
static constexpr size_t OFF_LAM   = 67829760;    // f32 120
static constexpr size_t OFF_OUTKB = 67830272;    // f32 120*512*128

__global__ __launch_bounds__(256) void k_tin(const float* __restrict__ x, unsigned short* __restrict__ xb) {
    int b = blockIdx.x >> 9, t = blockIdx.x & 511;
    __shared__ float ld[3840];
    const float* xp = x + ((size_t)b * 1966080 + (size_t)t * 30);
    for (int idx = threadIdx.x; idx < 3840; idx += 256) {
        int n = idx / 30, k = idx - n * 30;
        ld[idx] = xp[(size_t)n * 15360 + k];
    }
    __syncthreads();
    for (int idx = threadIdx.x; idx < 3840; idx += 256) {
        int k = idx >> 7, n = idx & 127;
        xb[(((size_t)(k * 4 + b)) * 512 + t) * 128 + n] = f2b(ld[n * 30 + k]);
    }
}

__global__ __launch_bounds__(256) void k_wcast(const float* __restrict__ Wq, const float* __restrict__ Wk,
        const float* __restrict__ Wv, const float* __restrict__ Wo,
        unsigned short* __restrict__ wq, unsigned short* __restrict__ wk,
        unsigned short* __restrict__ wv, unsigned short* __restrict__ wo) {
    int idx = blockIdx.x * 256 + threadIdx.x;
    if (idx < 491520)       wq[idx] = f2b(Wq[idx]);
    else if (idx < 983040)  wk[idx - 491520] = f2b(Wk[idx - 491520]);
    else if (idx < 1228800) wv[idx - 983040] = f2b(Wv[idx - 983040]);
    else if (idx < 1474560) wo[idx - 1228800] = f2b(Wo[idx - 1228800]);
}

// grid (kb=120, tile=8, z=2): same-kb blocks -> same XCD (120 % 8 == 0)
// z=0: q m-tiles 0..7 + v m-tiles 0,1 ; z=1: k m-tiles 0..7 + v m-tiles 2,3
__global__ __launch_bounds__(256) void k_qkv(const unsigned short* __restrict__ xb,
        const unsigned short* __restrict__ wq, const unsigned short* __restrict__ wk,
        const unsigned short* __restrict__ wv,
        unsigned short* __restrict__ qb, unsigned short* __restrict__ kb_, unsigned short* __restrict__ vT) {
    int kb = blockIdx.x, band = kb >> 2, z = blockIdx.z;
    int tid = threadIdx.x, lane = tid & 63;
    int t0 = blockIdx.y * 64 + (tid >> 6) * 16;
    int rA = lane & 15, kq = (lane >> 4) * 8;
    const unsigned short* ap = xb + ((size_t)kb * 512 + t0 + rA) * 128 + kq;
    bf16x8 a0 = *(const bf16x8*)(ap);
    bf16x8 a1 = *(const bf16x8*)(ap + 32);
    bf16x8 a2 = *(const bf16x8*)(ap + 64);
    bf16x8 a3 = *(const bf16x8*)(ap + 96);
    f32x4 zero = {};
    {
        const unsigned short* W = (z ? wk : wq) + (size_t)band * 16384;
        unsigned short* O = (z ? kb_ : qb);
#pragma unroll
        for (int mt = 0; mt < 8; ++mt) {
            int m0 = mt * 16;
            const unsigned short* bp = W + (size_t)(m0 + rA) * 128 + kq;
            bf16x8 b0 = *(const bf16x8*)(bp);
            bf16x8 b1 = *(const bf16x8*)(bp + 32);
            bf16x8 b2 = *(const bf16x8*)(bp + 64);
            bf16x8 b3 = *(const bf16x8*)(bp + 96);
            f32x4 c = zero;
            c = MFMA(a0, b0, c); c = MFMA(a1, b1, c); c = MFMA(a2, b2, c); c = MFMA(a3, b3, c);
#pragma unroll
            for (int r = 0; r < 4; ++r) {
                int t = t0 + (lane >> 4) * 4 + r;
                O[((size_t)kb * 512 + t) * 128 + m0 + rA] = f2b(c[r]);
            }
        }
    }
#pragma unroll
    for (int mi = 0; mi < 2; ++mi) {
        int m0 = (z * 2 + mi) * 16;
        const unsigned short* bp = wv + (size_t)band * 8192 + (size_t)(m0 + rA) * 128 + kq;
        bf16x8 b0 = *(const bf16x8*)(bp);
        bf16x8 b1 = *(const bf16x8*)(bp + 32);
        bf16x8 b2 = *(const bf16x8*)(bp + 64);
        bf16x8 b3 = *(const bf16x8*)(bp + 96);
        f32x4 c = zero;
        c = MFMA(a0, b0, c); c = MFMA(a1, b1, c); c = MFMA(a2, b2, c); c = MFMA(a3, b3, c);
#pragma unroll
        for (int r = 0; r < 4; ++r) {
            int t = t0 + (lane >> 4) * 4 + r;
            vT[((size_t)kb * 64 + m0 + rA) * 512 + t] = f2b(c[r]);
        }
    }
}

// grid (120,16): 32 rows/block; 4 waves = 2 t-groups x 2 s-halves (256 s each)
__global__ __launch_bounds__(256) void k_stats(const unsigned short* __restrict__ qb,
        const unsigned short* __restrict__ kb_, float* __restrict__ rowst) {
    int kb = blockIdx.x;
    int tid = threadIdx.x, lane = tid & 63, w = tid >> 6;
    int tg = w >> 1, sh = w & 1;
    int t0 = blockIdx.y * 32 + tg * 16;
    int rA = lane & 15, kq = (lane >> 4) * 8;
    __shared__ float sred[4][16][8];
    const unsigned short* qp = qb + ((size_t)kb * 512 + t0 + rA) * 128 + kq;
    bf16x8 qa0 = *(const bf16x8*)(qp);
    bf16x8 qa1 = *(const bf16x8*)(qp + 32);
    bf16x8 qa2 = *(const bf16x8*)(qp + 64);
    bf16x8 qa3 = *(const bf16x8*)(qp + 96);
    f32x4 zero = {};
    float sum1[4] = {}, ssq1[4] = {}, mx1[4], mn1[4];
    float sum2[4] = {}, ssq2[4] = {}, mx2[4], mn2[4];
#pragma unroll
    for (int r = 0; r < 4; ++r) { mx1[r] = -1e30f; mn1[r] = 1e30f; mx2[r] = -1e30f; mn2[r] = 1e30f; }
    const unsigned short* kbase = kb_ + (size_t)kb * 65536;
    int sbase = sh * 256;

    bf16x8 kA[8], kB[8];
    auto loadK = [&](int s0, bf16x8 (&kr)[8]) {
#pragma unroll
        for (int h = 0; h < 2; ++h) {
            const unsigned short* kp = kbase + (size_t)(s0 + h * 16 + rA) * 128 + kq;
#pragma unroll
            for (int i = 0; i < 4; ++i) kr[h * 4 + i] = *(const bf16x8*)(kp + i * 32);
        }
    };
    auto comp = [&](bf16x8 (&kr)[8]) {
#pragma unroll
        for (int h = 0; h < 2; ++h) {
            f32x4 c1 = MFMA(qa1, kr[h * 4 + 1], MFMA(qa0, kr[h * 4 + 0], zero));
            f32x4 c2 = MFMA(qa3, kr[h * 4 + 3], MFMA(qa2, kr[h * 4 + 2], zero));
#pragma unroll
            for (int r = 0; r < 4; ++r) {
                float lg = c1[r] * 0.25f;
                float e = __expf(lg);
                sum1[r] += e; ssq1[r] = fmaf(e, e, ssq1[r]);
                mx1[r] = fmaxf(mx1[r], lg); mn1[r] = fminf(mn1[r], lg);
                lg = c2[r] * 0.25f;
                e = __expf(lg);
                sum2[r] += e; ssq2[r] = fmaf(e, e, ssq2[r]);
                mx2[r] = fmaxf(mx2[r], lg); mn2[r] = fminf(mn2[r], lg);
            }
        }
    };
    loadK(sbase, kA);
#pragma unroll
    for (int it = 0; it < 8; ++it) {
        if ((it & 1) == 0) { if (it < 7) loadK(sbase + (it + 1) * 32, kB); comp(kA); }
        else               { if (it < 7) loadK(sbase + (it + 1) * 32, kA); comp(kB); }
    }
#pragma unroll
    for (int off = 1; off < 16; off <<= 1) {
#pragma unroll
        for (int r = 0; r < 4; ++r) {
            sum1[r] += __shfl_xor(sum1[r], off); ssq1[r] += __shfl_xor(ssq1[r], off);
            mx1[r] = fmaxf(mx1[r], __shfl_xor(mx1[r], off)); mn1[r] = fminf(mn1[r], __shfl_xor(mn1[r], off));
            sum2[r] += __shfl_xor(sum2[r], off); ssq2[r] += __shfl_xor(ssq2[r], off);
            mx2[r] = fmaxf(mx2[r], __shfl_xor(mx2[r], off)); mn2[r] = fminf(mn2[r], __shfl_xor(mn2[r], off));
        }
    }
    if (rA == 0) {
#pragma unroll
        for (int r = 0; r < 4; ++r) {
            int row = (lane >> 4) * 4 + r;
            sred[w][row][0] = sum1[r]; sred[w][row][1] = ssq1[r];
            sred[w][row][2] = mx1[r];  sred[w][row][3] = mn1[r];
            sred[w][row][4] = sum2[r]; sred[w][row][5] = ssq2[r];
            sred[w][row][6] = mx2[r];  sred[w][row][7] = mn2[r];
        }
    }
    __syncthreads();
    // 256 threads: 32 rows x 8 stats
    int row = tid >> 3, i = tid & 7;
    int tgc = row >> 4, r16 = row & 15;
    float a = sred[tgc * 2 + 0][r16][i];
    float b = sred[tgc * 2 + 1][r16][i];
    float c;
    if (i == 2 || i == 6)      c = fmaxf(a, b);
    else if (i == 3 || i == 7) c = fminf(a, b);
    else                       c = a + b;
    rowst[((size_t)kb * 512 + blockIdx.y * 32 + row) * 8 + i] = c;
}

__global__ __launch_bounds__(256) void k_lam(const float* __restrict__ rowst,
        const float* __restrict__ W1, const float* __restrict__ b1,
        const float* __restrict__ W2, const float* __restrict__ b2, float* __restrict__ lam) {
    int kb = blockIdx.x, band = kb >> 2;
    int tid = threadIdx.x;
    float ss1 = 0.f, mx1 = -1e30f, mn1 = 1e30f, ss2 = 0.f, mx2 = -1e30f, mn2 = 1e30f;
    for (int t = tid; t < 512; t += 256) {
        const float* r = rowst + ((size_t)kb * 512 + t) * 8;
        float is1 = 1.0f / r[0], is2 = 1.0f / r[4];
        ss1 += r[1] * is1 * is1;
        mx1 = fmaxf(mx1, __expf(r[2]) * is1); mn1 = fminf(mn1, __expf(r[3]) * is1);
        ss2 += r[5] * is2 * is2;
        mx2 = fmaxf(mx2, __expf(r[6]) * is2); mn2 = fminf(mn2, __expf(r[7]) * is2);
    }
    __shared__ float red[256 * 6];
    red[tid] = ss1; red[256 + tid] = mx1; red[512 + tid] = mn1;
    red[768 + tid] = ss2; red[1024 + tid] = mx2; red[1280 + tid] = mn2;
    __syncthreads();
    for (int h = 128; h > 0; h >>= 1) {
        if (tid < h) {
            red[tid] += red[tid + h];
            red[256 + tid] = fmaxf(red[256 + tid], red[256 + tid + h]);
            red[512 + tid] = fminf(red[512 + tid], red[512 + tid + h]);
            red[768 + tid] += red[768 + tid + h];
            red[1024 + tid] = fmaxf(red[1024 + tid], red[1024 + tid + h]);
            red[1280 + tid] = fminf(red[1280 + tid], red[1280 + tid + h]);
        }
        __syncthreads();
    }
    if (tid == 0) {
        float stats[8];
        stats[0] = 1.0f / 512.0f;
        stats[1] = sqrtf(fmaxf(red[0] - 1.0f, 0.0f) / 262143.0f);
        stats[2] = red[256]; stats[3] = red[512];
        stats[4] = 1.0f / 512.0f;
        stats[5] = sqrtf(fmaxf(red[768] - 1.0f, 0.0f) / 262143.0f);
        stats[6] = red[1024]; stats[7] = red[1280];
        float z = b2[band];
        for (int hh = 0; hh < 16; ++hh) {
            float a = b1[band * 16 + hh];
            for (int i = 0; i < 8; ++i) a += stats[i] * W1[band * 128 + hh * 8 + i];
            z += fmaxf(a, 0.0f) * W2[band * 16 + hh];
        }
        lam[kb] = 1.0f / (1.0f + __expf(-z));
    }
}

// grid (120,16): 32 rows/block; 4 waves = 2 t-groups x 2 s-halves; LDS combine of PV partials
__global__ __launch_bounds__(256) void k_pv(const unsigned short* __restrict__ qb,
        const unsigned short* __restrict__ kb_, const unsigned short* __restrict__ vT,
        const float* __restrict__ rowst, const float* __restrict__ lamv,
        unsigned short* __restrict__ omid) {
    int kb = blockIdx.x;
    int tid = threadIdx.x, lane = tid & 63, w = tid >> 6;
    int tg = w >> 1, sh = w & 1;
    int t0 = blockIdx.y * 32 + tg * 16;
    int rA = lane & 15, kq = (lane >> 4) * 8;
    __shared__ unsigned short plds[4][2][16 * 40];  // [wave][dbuf][row][40]
    __shared__ float pacc[2][16][64];               // [tg][row][v]
    const unsigned short* qp = qb + ((size_t)kb * 512 + t0 + rA) * 128 + kq;
    bf16x8 qa0 = *(const bf16x8*)(qp);
    bf16x8 qa1 = *(const bf16x8*)(qp + 32);
    bf16x8 qa2 = *(const bf16x8*)(qp + 64);
    bf16x8 qa3 = *(const bf16x8*)(qp + 96);
    float il1[4], il2[4];
#pragma unroll
    for (int r = 0; r < 4; ++r) {
        const float* rp = rowst + ((size_t)kb * 512 + t0 + (lane >> 4) * 4 + r) * 8;
        il1[r] = 1.0f / rp[0]; il2[r] = 1.0f / rp[4];
    }
    float lam = lamv[kb];
    f32x4 zero = {};
    f32x4 acc[4] = {zero, zero, zero, zero};
    const unsigned short* kbase = kb_ + (size_t)kb * 65536;
    const unsigned short* vbase = vT + (size_t)kb * 32768;
    int sbase = sh * 256;

    bf16x8 kA[8], kB[8], vA[4], vB[4];
    auto loadC = [&](int s0, bf16x8 (&kr)[8], bf16x8 (&vr)[4]) {
#pragma unroll
        for (int h = 0; h < 2; ++h) {
            const unsigned short* kp = kbase + (size_t)(s0 + h * 16 + rA) * 128 + kq;
#pragma unroll
            for (int i = 0; i < 4; ++i) kr[h * 4 + i] = *(const bf16x8*)(kp + i * 32);
        }
#pragma unroll
        for (int vt = 0; vt < 4; ++vt) vr[vt] = *(const bf16x8*)(vbase + (size_t)(vt * 16 + rA) * 512 + s0 + kq);
    };
    auto comp = [&](int it, bf16x8 (&kr)[8], bf16x8 (&vr)[4]) {
        int db = it & 1;
#pragma unroll
        for (int h = 0; h < 2; ++h) {
            f32x4 c1 = MFMA(qa1, kr[h * 4 + 1], MFMA(qa0, kr[h * 4 + 0], zero));
            f32x4 c2 = MFMA(qa3, kr[h * 4 + 3], MFMA(qa2, kr[h * 4 + 2], zero));
#pragma unroll
            for (int r = 0; r < 4; ++r) {
                float e1 = __expf(c1[r] * 0.25f) * il1[r];
                float e2 = __expf(c2[r] * 0.25f) * il2[r];
                plds[w][db][((lane >> 4) * 4 + r) * 40 + h * 16 + rA] = f2b(e1 - lam * e2);
            }
        }
        bf16x8 pa = *(const bf16x8*)(&plds[w][db][rA * 40 + kq]);
#pragma unroll
        for (int vt = 0; vt < 4; ++vt) acc[vt] = MFMA(pa, vr[vt], acc[vt]);
    };
    loadC(sbase, kA, vA);
#pragma unroll
    for (int it = 0; it < 8; ++it) {
        if ((it & 1) == 0) { if (it < 7) loadC(sbase + (it + 1) * 32, kB, vB); comp(it, kA, vA); }
        else               { if (it < 7) loadC(sbase + (it + 1) * 32, kA, vA); comp(it, kB, vB); }
    }
    if (sh == 1) {
#pragma unroll
        for (int vt = 0; vt < 4; ++vt)
#pragma unroll
            for (int r = 0; r < 4; ++r)
                pacc[tg][(lane >> 4) * 4 + r][vt * 16 + rA] = acc[vt][r];
    }
    __syncthreads();
    if (sh == 0) {
#pragma unroll
        for (int vt = 0; vt < 4; ++vt)
#pragma unroll
            for (int r = 0; r < 4; ++r) {
                int t = t0 + (lane >> 4) * 4 + r;
                float o = acc[vt][r] + pacc[tg][(lane >> 4) * 4 + r][vt * 16 + rA];
                omid[((size_t)kb * 512 + t) * 64 + vt * 16 + rA] = f2b(o);
            }
    }
}

// grid (120,8,2): z -> m-tiles 0..3 / 4..7
__global__ __launch_bounds__(256) void k_wo(const unsigned short* __restrict__ omid,
        const unsigned short* __restrict__ wo, const float* __restrict__ bo,
        float* __restrict__ outkb) {
    int kb = blockIdx.x, band = kb >> 2, z = blockIdx.z;
    int tid = threadIdx.x, lane = tid & 63;
    int t0 = blockIdx.y * 64 + (tid >> 6) * 16;
    int rA = lane & 15, kq = (lane >> 4) * 8;
    const unsigned short* ap = omid + ((size_t)kb * 512 + t0 + rA) * 64 + kq;
    bf16x8 a0 = *(const bf16x8*)(ap);
    bf16x8 a1 = *(const bf16x8*)(ap + 32);
    f32x4 zero = {};
#pragma unroll
    for (int mi = 0; mi < 4; ++mi) {
        int m0 = (z * 4 + mi) * 16;
        const unsigned short* bp = wo + (size_t)band * 8192 + (size_t)(m0 + rA) * 64 + kq;
        bf16x8 b0 = *(const bf16x8*)(bp);
        bf16x8 b1 = *(const bf16x8*)(bp + 32);
        f32x4 c = MFMA(a1, b1, MFMA(a0, b0, zero));
        float bias = bo[band * 128 + m0 + rA];
#pragma unroll
        for (int r = 0; r < 4; ++r) {
            int t = t0 + (lane >> 4) * 4 + r;
            outkb[((size_t)kb * 512 + t) * 128 + m0 + rA] = c[r] + bias;
        }
    }
}

__global__ __launch_bounds__(256) void k_tout(const float* __restrict__ outkb, float* __restrict__ out) {
    int b = blockIdx.x >> 9, t = blockIdx.x & 511;
    __shared__ float ld[30 * 129];
    for (int idx = threadIdx.x; idx < 3840; idx += 256) {
        int k = idx >> 7, n = idx & 127;
        ld[k * 129 + n] = outkb[(((size_t)(k * 4 + b)) * 512 + t) * 128 + n];
    }
    __syncthreads();
    float* op = out + ((size_t)b * 1966080 + (size_t)t * 30);
    for (int idx = threadIdx.x; idx < 3840; idx += 256) {
        int n = idx / 30, k = idx - n * 30;
        op[(size_t)n * 15360 + k] = ld[k * 129 + n];
    }
}

extern "C" void kernel_launch(void* const* d_in, const int* in_sizes, int n_in,
                              void* d_out, int out_size, void* d_ws, size_t ws_size,
                              hipStream_t stream) {
    (void)in_sizes; (void)n_in; (void)out_size; (void)ws_size;
    const float* x  = (const float*)d_in[0];
    const float* Wq = (const float*)d_in[1];
    const float* Wk = (const float*)d_in[2];
    const float* Wv = (const float*)d_in[3];
    const float* Wo = (const float*)d_in[4];
    const float* bo = (const float*)d_in[5];
    const float* W1 = (const float*)d_in[6];
    const float* b1 = (const float*)d_in[7];
    const float* W2 = (const float*)d_in[8];
    const float* b2 = (const float*)d_in[9];
    float* out = (float*)d_out;
    char* ws = (char*)d_ws;

    unsigned short* xb  = (unsigned short*)(ws + OFF_XB);
    unsigned short* qb  = (unsigned short*)(ws + OFF_Q);
    unsigned short* kbb = (unsigned short*)(ws + OFF_K);
    unsigned short* vT  = (unsigned short*)(ws + OFF_VT);
    unsigned short* om  = (unsigned short*)(ws + OFF_OM);
    unsigned short* wqb = (unsigned short*)(ws + OFF_WQ);
    unsigned short* wkb = (unsigned short*)(ws + OFF_WK);
    unsigned short* wvb = (unsigned short*)(ws + OFF_WV);
    unsigned short* wob = (unsigned short*)(ws + OFF_WO);
    float* rowst = (float*)(ws + OFF_RS);
    float* lam   = (float*)(ws + OFF_LAM);
    float* outkb = (float*)(ws + OFF_OUTKB);

    k_tin  <<<2048, 256, 0, stream>>>(x, xb);
    k_wcast<<<5760, 256, 0, stream>>>(Wq, Wk, Wv, Wo, wqb, wkb, wvb, wob);
    k_qkv  <<<dim3(120, 8, 2), 256, 0, stream>>>(xb, wqb, wkb, wvb, qb, kbb, vT);
    k_stats<<<dim3(120, 16), 256, 0, stream>>>(qb, kbb, rowst);
    k_lam  <<<120, 256, 0, stream>>>(rowst, W1, b1, W2, b2, lam);
    k_pv   <<<dim3(120, 16), 256, 0, stream>>>(qb, kbb, vT, rowst, lam, om);
    k_wo   <<<dim3(120, 8, 2), 256, 0, stream>>>(om, wob, bo, outkb);
    k_tout <<<2048, 256, 0, stream>>>(outkb, out);
}

// Round 5
// 244.315 us; speedup vs baseline: 1.3990x; 1.3990x over previous
//
#include <hip/hip_runtime.h>
#include <math.h>

// K=30 bands, B=4, T=512, N=128, Vd=64, NKB=120
typedef __attribute__((ext_vector_type(8))) short bf16x8;
typedef __attribute__((ext_vector_type(4))) float f32x4;

#define MFMA(a, b, c) __builtin_amdgcn_mfma_f32_16x16x32_bf16((a), (b), (c), 0, 0, 0)

__device__ inline unsigned short f2b(float f) {
    unsigned u = __builtin_bit_cast(unsigned, f);
    u += 0x7FFF + ((u >> 16) & 1);
    return (unsigned short)(u >> 16);
}

typedef const __attribute__((address_space(1))) unsigned glb_u32;
typedef __attribute__((address_space(3))) unsigned lds_u32;
__device__ inline void gl_lds16(const void* g, void* l) {
    __builtin_amdgcn_global_load_lds((glb_u32*)g, (lds_u32*)l, 16, 0, 0);
}

// ws byte offsets
static constexpr size_t OFF_XB    = 0;           // bf16 120*512*128
static constexpr size_t OFF_Q     = 15728640;    // bf16 120*512*128
static constexpr size_t OFF_K     = 31457280;    // bf16 120*512*128
static constexpr size_t OFF_VT    = 47185920;    // bf16 120*64*512
static constexpr size_t OFF_WQ    = 55050240;    // bf16 30*128*128
static constexpr size_t OFF_WK    = 56033280;    // bf16 30*128*128
static constexpr size_t OFF_WV    = 57016320;    // bf16 30*64*128
static constexpr size_t OFF_WO    = 57507840;    // bf16 30*128*64
static constexpr size_t OFF_RS    = 57999360;    // f32 120*512*8
static constexpr size_t OFF_LAM   = 59965440;    // f32 120
static constexpr size_t OFF_U1    = 59965952;    // f32 120*512*64
static constexpr size_t OFF_U2    = 75694592;    // f32 120*512*64
static constexpr size_t OFF_OUTKB = 91423232;    // f32 120*512*128  (end ~117 MB)

__global__ __launch_bounds__(256) void k_tin(const float* __restrict__ x, unsigned short* __restrict__ xb) {
    int b = blockIdx.x >> 9, t = blockIdx.x & 511;
    __shared__ float ld[3840];
    const float* xp = x + ((size_t)b * 1966080 + (size_t)t * 30);
    for (int idx = threadIdx.x; idx < 3840; idx += 256) {
        int n = idx / 30, k = idx - n * 30;
        ld[idx] = xp[(size_t)n * 15360 + k];
    }
    __syncthreads();
    for (int idx = threadIdx.x; idx < 3840; idx += 256) {
        int k = idx >> 7, n = idx & 127;
        xb[(((size_t)(k * 4 + b)) * 512 + t) * 128 + n] = f2b(ld[n * 30 + k]);
    }
}

__global__ __launch_bounds__(256) void k_wcast(const float* __restrict__ Wq, const float* __restrict__ Wk,
        const float* __restrict__ Wv, const float* __restrict__ Wo,
        unsigned short* __restrict__ wq, unsigned short* __restrict__ wk,
        unsigned short* __restrict__ wv, unsigned short* __restrict__ wo) {
    int idx = blockIdx.x * 256 + threadIdx.x;
    if (idx < 491520)       wq[idx] = f2b(Wq[idx]);
    else if (idx < 983040)  wk[idx - 491520] = f2b(Wk[idx - 491520]);
    else if (idx < 1228800) wv[idx - 983040] = f2b(Wv[idx - 983040]);
    else if (idx < 1474560) wo[idx - 1228800] = f2b(Wo[idx - 1228800]);
}

// grid (kb=120, tile=8, z=2): same-kb blocks -> same XCD (120 % 8 == 0)
__global__ __launch_bounds__(256) void k_qkv(const unsigned short* __restrict__ xb,
        const unsigned short* __restrict__ wq, const unsigned short* __restrict__ wk,
        const unsigned short* __restrict__ wv,
        unsigned short* __restrict__ qb, unsigned short* __restrict__ kb_, unsigned short* __restrict__ vT) {
    int kb = blockIdx.x, band = kb >> 2, z = blockIdx.z;
    int tid = threadIdx.x, lane = tid & 63;
    int t0 = blockIdx.y * 64 + (tid >> 6) * 16;
    int rA = lane & 15, kq = (lane >> 4) * 8;
    const unsigned short* ap = xb + ((size_t)kb * 512 + t0 + rA) * 128 + kq;
    bf16x8 a0 = *(const bf16x8*)(ap);
    bf16x8 a1 = *(const bf16x8*)(ap + 32);
    bf16x8 a2 = *(const bf16x8*)(ap + 64);
    bf16x8 a3 = *(const bf16x8*)(ap + 96);
    f32x4 zero = {};
    {
        const unsigned short* W = (z ? wk : wq) + (size_t)band * 16384;
        unsigned short* O = (z ? kb_ : qb);
#pragma unroll
        for (int mt = 0; mt < 8; ++mt) {
            int m0 = mt * 16;
            const unsigned short* bp = W + (size_t)(m0 + rA) * 128 + kq;
            bf16x8 b0 = *(const bf16x8*)(bp);
            bf16x8 b1 = *(const bf16x8*)(bp + 32);
            bf16x8 b2 = *(const bf16x8*)(bp + 64);
            bf16x8 b3 = *(const bf16x8*)(bp + 96);
            f32x4 c = zero;
            c = MFMA(a0, b0, c); c = MFMA(a1, b1, c); c = MFMA(a2, b2, c); c = MFMA(a3, b3, c);
#pragma unroll
            for (int r = 0; r < 4; ++r) {
                int t = t0 + (lane >> 4) * 4 + r;
                O[((size_t)kb * 512 + t) * 128 + m0 + rA] = f2b(c[r]);
            }
        }
    }
#pragma unroll
    for (int mi = 0; mi < 2; ++mi) {
        int m0 = (z * 2 + mi) * 16;
        const unsigned short* bp = wv + (size_t)band * 8192 + (size_t)(m0 + rA) * 128 + kq;
        bf16x8 b0 = *(const bf16x8*)(bp);
        bf16x8 b1 = *(const bf16x8*)(bp + 32);
        bf16x8 b2 = *(const bf16x8*)(bp + 64);
        bf16x8 b3 = *(const bf16x8*)(bp + 96);
        f32x4 c = zero;
        c = MFMA(a0, b0, c); c = MFMA(a1, b1, c); c = MFMA(a2, b2, c); c = MFMA(a3, b3, c);
#pragma unroll
        for (int r = 0; r < 4; ++r) {
            int t = t0 + (lane >> 4) * 4 + r;
            vT[((size_t)kb * 64 + m0 + rA) * 512 + t] = f2b(c[r]);
        }
    }
}

// Fused stats+PV: per block 64 t-rows, full s range.
// LDS-staged K (32x128, XOR-swz) + V (64x32, XOR-swz) double-buffered via global_load_lds.
// Outputs raw u1=e1^T V, u2=e2^T V (f32) and raw row stats (sum, ssq, max, min) per map.
__global__ __launch_bounds__(256) void k_fused(const unsigned short* __restrict__ qb,
        const unsigned short* __restrict__ kb_, const unsigned short* __restrict__ vT,
        float* __restrict__ u1, float* __restrict__ u2, float* __restrict__ rowst) {
    int kb = blockIdx.x;
    int tid = threadIdx.x, lane = tid & 63, w = tid >> 6;
    int tw = blockIdx.y * 64 + w * 16;
    int rA = lane & 15, g = lane >> 4, kq8 = g * 8, g16 = g * 16;

    __shared__ __attribute__((aligned(16))) char kls[2][8192];
    __shared__ __attribute__((aligned(16))) char vls[2][4096];
    __shared__ __attribute__((aligned(16))) unsigned short plds[4][2][640];

    const unsigned short* qp = qb + ((size_t)kb * 512 + tw + rA) * 128 + kq8;
    bf16x8 qa0 = *(const bf16x8*)(qp);
    bf16x8 qa1 = *(const bf16x8*)(qp + 32);
    bf16x8 qa2 = *(const bf16x8*)(qp + 64);
    bf16x8 qa3 = *(const bf16x8*)(qp + 96);

    const char* kglob = (const char*)(kb_ + (size_t)kb * 65536);
    const char* vglob = (const char*)(vT + (size_t)kb * 32768);

    f32x4 zero = {};
    f32x4 u1a[4] = {zero, zero, zero, zero};
    f32x4 u2a[4] = {zero, zero, zero, zero};
    float sum1[4] = {}, ssq1[4] = {}, mx1[4], mn1[4];
    float sum2[4] = {}, ssq2[4] = {}, mx2[4], mn2[4];
#pragma unroll
    for (int r = 0; r < 4; ++r) { mx1[r] = -1e30f; mn1[r] = 1e30f; mx2[r] = -1e30f; mn2[r] = 1e30f; }

    auto stage = [&](int s0, int buf) {
#pragma unroll
        for (int j = 0; j < 2; ++j) {
            int bib = j * 4096 + w * 1024 + lane * 16;
            int row = bib >> 8;
            int col = (bib & 255) ^ ((row & 7) << 4);
            gl_lds16(kglob + (size_t)(s0 + row) * 256 + col, &kls[buf][j * 4096 + w * 1024]);
        }
        int bib = w * 1024 + lane * 16;
        int row = bib >> 6;
        int col = (bib & 63) ^ (((row >> 1) & 3) << 4);
        gl_lds16(vglob + (size_t)row * 1024 + (size_t)s0 * 2 + col, &vls[buf][w * 1024]);
    };

    auto compute = [&](int buf) {
        const char* kc = kls[buf];
        const char* vc = vls[buf];
        int sw = (rA & 7) << 4;
#pragma unroll
        for (int h = 0; h < 2; ++h) {
            int krow = h * 16 + rA;
            bf16x8 k0 = *(const bf16x8*)(kc + krow * 256 + ((g16 +   0) ^ sw));
            bf16x8 k1 = *(const bf16x8*)(kc + krow * 256 + ((g16 +  64) ^ sw));
            bf16x8 k2 = *(const bf16x8*)(kc + krow * 256 + ((g16 + 128) ^ sw));
            bf16x8 k3 = *(const bf16x8*)(kc + krow * 256 + ((g16 + 192) ^ sw));
            f32x4 c1 = MFMA(qa1, k1, MFMA(qa0, k0, zero));
            f32x4 c2 = MFMA(qa3, k3, MFMA(qa2, k2, zero));
#pragma unroll
            for (int r = 0; r < 4; ++r) {
                float lg = c1[r] * 0.25f;
                float e = __expf(lg);
                sum1[r] += e; ssq1[r] = fmaf(e, e, ssq1[r]);
                mx1[r] = fmaxf(mx1[r], lg); mn1[r] = fminf(mn1[r], lg);
                plds[w][0][(g * 4 + r) * 40 + h * 16 + rA] = f2b(e);
                lg = c2[r] * 0.25f;
                e = __expf(lg);
                sum2[r] += e; ssq2[r] = fmaf(e, e, ssq2[r]);
                mx2[r] = fmaxf(mx2[r], lg); mn2[r] = fminf(mn2[r], lg);
                plds[w][1][(g * 4 + r) * 40 + h * 16 + rA] = f2b(e);
            }
        }
        bf16x8 pa1 = *(const bf16x8*)&plds[w][0][rA * 40 + kq8];
        bf16x8 pa2 = *(const bf16x8*)&plds[w][1][rA * 40 + kq8];
#pragma unroll
        for (int vt = 0; vt < 4; ++vt) {
            int vrow = vt * 16 + rA;
            bf16x8 vf = *(const bf16x8*)(vc + vrow * 64 + (g16 ^ (((vrow >> 1) & 3) << 4)));
            u1a[vt] = MFMA(pa1, vf, u1a[vt]);
            u2a[vt] = MFMA(pa2, vf, u2a[vt]);
        }
    };

    stage(0, 0);
    for (int it = 0; it < 16; ++it) {
        int cur = it & 1;
        if (it < 15) {
            stage((it + 1) * 32, cur ^ 1);
            asm volatile("s_waitcnt vmcnt(3)" ::: "memory");
        } else {
            asm volatile("s_waitcnt vmcnt(0)" ::: "memory");
        }
        __builtin_amdgcn_s_barrier();
        asm volatile("" ::: "memory");
        compute(cur);
        asm volatile("" ::: "memory");
        __builtin_amdgcn_s_barrier();
    }

    // stats reduce across rA lanes (s-direction)
#pragma unroll
    for (int off = 1; off < 16; off <<= 1) {
#pragma unroll
        for (int r = 0; r < 4; ++r) {
            sum1[r] += __shfl_xor(sum1[r], off); ssq1[r] += __shfl_xor(ssq1[r], off);
            mx1[r] = fmaxf(mx1[r], __shfl_xor(mx1[r], off)); mn1[r] = fminf(mn1[r], __shfl_xor(mn1[r], off));
            sum2[r] += __shfl_xor(sum2[r], off); ssq2[r] += __shfl_xor(ssq2[r], off);
            mx2[r] = fmaxf(mx2[r], __shfl_xor(mx2[r], off)); mn2[r] = fminf(mn2[r], __shfl_xor(mn2[r], off));
        }
    }
    if (rA == 0) {
#pragma unroll
        for (int r = 0; r < 4; ++r) {
            float* rp = rowst + ((size_t)kb * 512 + tw + g * 4 + r) * 8;
            rp[0] = sum1[r]; rp[1] = ssq1[r]; rp[2] = mx1[r]; rp[3] = mn1[r];
            rp[4] = sum2[r]; rp[5] = ssq2[r]; rp[6] = mx2[r]; rp[7] = mn2[r];
        }
    }
#pragma unroll
    for (int vt = 0; vt < 4; ++vt)
#pragma unroll
        for (int r = 0; r < 4; ++r) {
            int t = tw + g * 4 + r;
            u1[((size_t)kb * 512 + t) * 64 + vt * 16 + rA] = u1a[vt][r];
            u2[((size_t)kb * 512 + t) * 64 + vt * 16 + rA] = u2a[vt][r];
        }
}

__global__ __launch_bounds__(256) void k_lam(const float* __restrict__ rowst,
        const float* __restrict__ W1, const float* __restrict__ b1,
        const float* __restrict__ W2, const float* __restrict__ b2, float* __restrict__ lam) {
    int kb = blockIdx.x, band = kb >> 2;
    int tid = threadIdx.x;
    float ss1 = 0.f, mx1 = -1e30f, mn1 = 1e30f, ss2 = 0.f, mx2 = -1e30f, mn2 = 1e30f;
    for (int t = tid; t < 512; t += 256) {
        const float* r = rowst + ((size_t)kb * 512 + t) * 8;
        float is1 = 1.0f / r[0], is2 = 1.0f / r[4];
        ss1 += r[1] * is1 * is1;
        mx1 = fmaxf(mx1, __expf(r[2]) * is1); mn1 = fminf(mn1, __expf(r[3]) * is1);
        ss2 += r[5] * is2 * is2;
        mx2 = fmaxf(mx2, __expf(r[6]) * is2); mn2 = fminf(mn2, __expf(r[7]) * is2);
    }
    __shared__ float red[256 * 6];
    red[tid] = ss1; red[256 + tid] = mx1; red[512 + tid] = mn1;
    red[768 + tid] = ss2; red[1024 + tid] = mx2; red[1280 + tid] = mn2;
    __syncthreads();
    for (int h = 128; h > 0; h >>= 1) {
        if (tid < h) {
            red[tid] += red[tid + h];
            red[256 + tid] = fmaxf(red[256 + tid], red[256 + tid + h]);
            red[512 + tid] = fminf(red[512 + tid], red[512 + tid + h]);
            red[768 + tid] += red[768 + tid + h];
            red[1024 + tid] = fmaxf(red[1024 + tid], red[1024 + tid + h]);
            red[1280 + tid] = fminf(red[1280 + tid], red[1280 + tid + h]);
        }
        __syncthreads();
    }
    if (tid == 0) {
        float stats[8];
        stats[0] = 1.0f / 512.0f;
        stats[1] = sqrtf(fmaxf(red[0] - 1.0f, 0.0f) / 262143.0f);
        stats[2] = red[256]; stats[3] = red[512];
        stats[4] = 1.0f / 512.0f;
        stats[5] = sqrtf(fmaxf(red[768] - 1.0f, 0.0f) / 262143.0f);
        stats[6] = red[1024]; stats[7] = red[1280];
        float z = b2[band];
        for (int hh = 0; hh < 16; ++hh) {
            float a = b1[band * 16 + hh];
            for (int i = 0; i < 8; ++i) a += stats[i] * W1[band * 128 + hh * 8 + i];
            z += fmaxf(a, 0.0f) * W2[band * 16 + hh];
        }
        lam[kb] = 1.0f / (1.0f + __expf(-z));
    }
}

// out = ((u1*il1 - lam*u2*il2) @ Wo^T) + bo ; A built on the fly from f32 u's
__global__ __launch_bounds__(256) void k_wo(const float* __restrict__ u1, const float* __restrict__ u2,
        const float* __restrict__ rowst, const float* __restrict__ lamv,
        const unsigned short* __restrict__ wo, const float* __restrict__ bo,
        float* __restrict__ outkb) {
    int kb = blockIdx.x, band = kb >> 2, z = blockIdx.z;
    int tid = threadIdx.x, lane = tid & 63;
    int t0 = blockIdx.y * 64 + (tid >> 6) * 16;
    int rA = lane & 15, kq = (lane >> 4) * 8;
    int t = t0 + rA;
    const float* rp = rowst + ((size_t)kb * 512 + t) * 8;
    float il1 = 1.0f / rp[0], il2l = lamv[kb] / rp[4];
    const float* u1p = u1 + ((size_t)kb * 512 + t) * 64 + kq;
    const float* u2p = u2 + ((size_t)kb * 512 + t) * 64 + kq;
    bf16x8 a0, a1;
#pragma unroll
    for (int half = 0; half < 2; ++half) {
        float4 x1 = *(const float4*)(u1p + half * 32);
        float4 y1 = *(const float4*)(u1p + half * 32 + 4);
        float4 x2 = *(const float4*)(u2p + half * 32);
        float4 y2 = *(const float4*)(u2p + half * 32 + 4);
        float o[8];
        o[0] = x1.x * il1 - x2.x * il2l; o[1] = x1.y * il1 - x2.y * il2l;
        o[2] = x1.z * il1 - x2.z * il2l; o[3] = x1.w * il1 - x2.w * il2l;
        o[4] = y1.x * il1 - y2.x * il2l; o[5] = y1.y * il1 - y2.y * il2l;
        o[6] = y1.z * il1 - y2.z * il2l; o[7] = y1.w * il1 - y2.w * il2l;
        if (half == 0) {
#pragma unroll
            for (int j = 0; j < 8; ++j) a0[j] = (short)f2b(o[j]);
        } else {
#pragma unroll
            for (int j = 0; j < 8; ++j) a1[j] = (short)f2b(o[j]);
        }
    }
    f32x4 zero = {};
#pragma unroll
    for (int mi = 0; mi < 4; ++mi) {
        int m0 = (z * 4 + mi) * 16;
        const unsigned short* bp = wo + (size_t)band * 8192 + (size_t)(m0 + rA) * 64 + kq;
        bf16x8 b0 = *(const bf16x8*)(bp);
        bf16x8 b1 = *(const bf16x8*)(bp + 32);
        f32x4 c = MFMA(a1, b1, MFMA(a0, b0, zero));
        float bias = bo[band * 128 + m0 + rA];
#pragma unroll
        for (int r = 0; r < 4; ++r) {
            int tt = t0 + (lane >> 4) * 4 + r;
            outkb[((size_t)kb * 512 + tt) * 128 + m0 + rA] = c[r] + bias;
        }
    }
}

__global__ __launch_bounds__(256) void k_tout(const float* __restrict__ outkb, float* __restrict__ out) {
    int b = blockIdx.x >> 9, t = blockIdx.x & 511;
    __shared__ float ld[30 * 129];
    for (int idx = threadIdx.x; idx < 3840; idx += 256) {
        int k = idx >> 7, n = idx & 127;
        ld[k * 129 + n] = outkb[(((size_t)(k * 4 + b)) * 512 + t) * 128 + n];
    }
    __syncthreads();
    float* op = out + ((size_t)b * 1966080 + (size_t)t * 30);
    for (int idx = threadIdx.x; idx < 3840; idx += 256) {
        int n = idx / 30, k = idx - n * 30;
        op[(size_t)n * 15360 + k] = ld[k * 129 + n];
    }
}

extern "C" void kernel_launch(void* const* d_in, const int* in_sizes, int n_in,
                              void* d_out, int out_size, void* d_ws, size_t ws_size,
                              hipStream_t stream) {
    (void)in_sizes; (void)n_in; (void)out_size; (void)ws_size;
    const float* x  = (const float*)d_in[0];
    const float* Wq = (const float*)d_in[1];
    const float* Wk = (const float*)d_in[2];
    const float* Wv = (const float*)d_in[3];
    const float* Wo = (const float*)d_in[4];
    const float* bo = (const float*)d_in[5];
    const float* W1 = (const float*)d_in[6];
    const float* b1 = (const float*)d_in[7];
    const float* W2 = (const float*)d_in[8];
    const float* b2 = (const float*)d_in[9];
    float* out = (float*)d_out;
    char* ws = (char*)d_ws;

    unsigned short* xb  = (unsigned short*)(ws + OFF_XB);
    unsigned short* qb  = (unsigned short*)(ws + OFF_Q);
    unsigned short* kbb = (unsigned short*)(ws + OFF_K);
    unsigned short* vT  = (unsigned short*)(ws + OFF_VT);
    unsigned short* wqb = (unsigned short*)(ws + OFF_WQ);
    unsigned short* wkb = (unsigned short*)(ws + OFF_WK);
    unsigned short* wvb = (unsigned short*)(ws + OFF_WV);
    unsigned short* wob = (unsigned short*)(ws + OFF_WO);
    float* rowst = (float*)(ws + OFF_RS);
    float* lam   = (float*)(ws + OFF_LAM);
    float* u1    = (float*)(ws + OFF_U1);
    float* u2    = (float*)(ws + OFF_U2);
    float* outkb = (float*)(ws + OFF_OUTKB);

    k_tin  <<<2048, 256, 0, stream>>>(x, xb);
    k_wcast<<<5760, 256, 0, stream>>>(Wq, Wk, Wv, Wo, wqb, wkb, wvb, wob);
    k_qkv  <<<dim3(120, 8, 2), 256, 0, stream>>>(xb, wqb, wkb, wvb, qb, kbb, vT);
    k_fused<<<dim3(120, 8), 256, 0, stream>>>(qb, kbb, vT, u1, u2, rowst);
    k_lam  <<<120, 256, 0, stream>>>(rowst, W1, b1, W2, b2, lam);
    k_wo   <<<dim3(120, 8, 2), 256, 0, stream>>>(u1, u2, rowst, lam, wob, bo, outkb);
    k_tout <<<2048, 256, 0, stream>>>(outkb, out);
}